// Round 4
// baseline (6481.397 us; speedup 1.0000x reference)
//
#include <hip/hip_runtime.h>
#include <hip/hip_bf16.h>

#define NN 50000
#define TT 8
#define EE 1600000

constexpr int SCAN_B = 512;
constexpr int NBLK = (NN + SCAN_B - 1) / SCAN_B; // 98

// ---------------- utility kernels ----------------
__global__ void k_zero4(float4* p, long n4) {
  long i = (long)blockIdx.x * blockDim.x + threadIdx.x;
  if (i < n4) p[i] = make_float4(0.f, 0.f, 0.f, 0.f);
}

__global__ void k_zeroi(int* p, int n) {
  int i = blockIdx.x * blockDim.x + threadIdx.x;
  if (i < n) p[i] = 0;
}

// ---------------- CSR build ----------------
__global__ void k_count(const int* __restrict__ row, int* __restrict__ deg) {
  int e = blockIdx.x * blockDim.x + threadIdx.x;
  if (e < EE) atomicAdd(&deg[row[e]], 1);
}

__global__ void k_scan1(const int* __restrict__ deg, int* __restrict__ rs, int* __restrict__ bsum) {
  __shared__ int s[SCAN_B];
  int t = threadIdx.x;
  int i = blockIdx.x * SCAN_B + t;
  int v = (i < NN) ? deg[i] : 0;
  s[t] = v;
  __syncthreads();
  for (int off = 1; off < SCAN_B; off <<= 1) {
    int add = (t >= off) ? s[t - off] : 0;
    __syncthreads();
    s[t] += add;
    __syncthreads();
  }
  if (i < NN) rs[i] = s[t] - v;          // exclusive within block
  if (t == SCAN_B - 1) bsum[blockIdx.x] = s[t];
}

__global__ void k_scan2(int* __restrict__ bsum) {
  __shared__ int s[128];
  int t = threadIdx.x;
  int v = (t < NBLK) ? bsum[t] : 0;
  s[t] = v;
  __syncthreads();
  for (int off = 1; off < 128; off <<= 1) {
    int add = (t >= off) ? s[t - off] : 0;
    __syncthreads();
    s[t] += add;
    __syncthreads();
  }
  if (t < NBLK) bsum[t] = s[t] - v;      // exclusive block offsets
}

__global__ void k_scan3(int* __restrict__ rs, const int* __restrict__ bsum, const int* __restrict__ deg,
                        float* __restrict__ dinv, int* __restrict__ cursor) {
  int i = blockIdx.x * blockDim.x + threadIdx.x;
  if (i < NN) {
    int v = rs[i] + bsum[i / SCAN_B];
    rs[i] = v;
    cursor[i] = v;
    dinv[i] = rsqrtf((float)(deg[i] + 1));   // +1 self-loop
  }
  if (i == 0) rs[NN] = EE;                   // total = E exactly
}

__global__ void k_scatter(const int* __restrict__ row, const int* __restrict__ col,
                          int* __restrict__ cursor, int* __restrict__ csr) {
  int e = blockIdx.x * blockDim.x + threadIdx.x;
  if (e < EE) {
    int r = row[e];
    int p = atomicAdd(&cursor[r], 1);
    csr[p] = col[e];
  }
}

// ---------------- GEMM: C[N,128] = A[N,128] @ W[128,128] (NN layout) ----------------
__launch_bounds__(256) __global__
void k_gemm_nn(const float* __restrict__ A, const float* __restrict__ W, float* __restrict__ C) {
  __shared__ float As[32][132];   // +4 pad: conflict-free row-strided reads
  int t = threadIdx.x;
  int row0 = blockIdx.x * 32;
  {
    int lr = t >> 3, lk = (t & 7) * 4;
    bool rok = (row0 + lr) < NN;
    const float* ar = A + (long)(row0 + lr) * 128;
#pragma unroll
    for (int i = 0; i < 4; i++) {
      float4 v = rok ? *(const float4*)(ar + lk + i * 32) : make_float4(0.f, 0.f, 0.f, 0.f);
      *(float4*)&As[lr][lk + i * 32] = v;
    }
  }
  __syncthreads();
  int cg = (t & 31) * 4;        // output col (4 wide)
  int rg = (t >> 5) * 4;        // output row group (4 rows)
  float4 acc[4];
#pragma unroll
  for (int r = 0; r < 4; r++) acc[r] = make_float4(0.f, 0.f, 0.f, 0.f);
  for (int k = 0; k < 128; k += 4) {
    float4 a[4], w[4];
#pragma unroll
    for (int r = 0; r < 4; r++) a[r] = *(float4*)&As[rg + r][k];
#pragma unroll
    for (int i = 0; i < 4; i++) w[i] = *(const float4*)(W + (long)(k + i) * 128 + cg);
#pragma unroll
    for (int r = 0; r < 4; r++) {
      acc[r].x += a[r].x * w[0].x + a[r].y * w[1].x + a[r].z * w[2].x + a[r].w * w[3].x;
      acc[r].y += a[r].x * w[0].y + a[r].y * w[1].y + a[r].z * w[2].y + a[r].w * w[3].y;
      acc[r].z += a[r].x * w[0].z + a[r].y * w[1].z + a[r].z * w[2].z + a[r].w * w[3].z;
      acc[r].w += a[r].x * w[0].w + a[r].y * w[1].w + a[r].z * w[2].w + a[r].w * w[3].w;
    }
  }
#pragma unroll
  for (int r = 0; r < 4; r++) {
    int row = row0 + rg + r;
    if (row < NN) *(float4*)&C[(long)row * 128 + cg] = acc[r];
  }
}

// ---------------- GCN aggregation: one wave per dest node ----------------
__launch_bounds__(256) __global__
void k_agg(const float* __restrict__ Hm, const float* __restrict__ dinv,
           const int* __restrict__ rs, const int* __restrict__ csr,
           const float* __restrict__ bias, float* __restrict__ out) {
  int i = blockIdx.x * 4 + (threadIdx.x >> 6);
  int lane = threadIdx.x & 63;
  if (i >= NN) return;
  float di = dinv[i];
  const float2* H2 = (const float2*)Hm;
  float2 a = H2[(long)i * 64 + lane];
  float sw = di * di;                      // self-loop norm
  float2 acc;
  acc.x = a.x * sw;
  acc.y = a.y * sw;
  int e0 = rs[i], e1 = rs[i + 1];
  int e = e0;
  for (; e + 2 <= e1; e += 2) {            // 2-deep for load ILP
    int c0 = csr[e], c1 = csr[e + 1];
    float w0 = di * dinv[c0], w1 = di * dinv[c1];
    float2 v0 = H2[(long)c0 * 64 + lane];
    float2 v1 = H2[(long)c1 * 64 + lane];
    acc.x += w0 * v0.x + w1 * v1.x;
    acc.y += w0 * v0.y + w1 * v1.y;
  }
  if (e < e1) {
    int c0 = csr[e];
    float w0 = di * dinv[c0];
    float2 v0 = H2[(long)c0 * 64 + lane];
    acc.x += w0 * v0.x;
    acc.y += w0 * v0.y;
  }
  float2 b = ((const float2*)bias)[lane];
  float2 r;
  r.x = fmaxf(acc.x + b.x, 0.f);
  r.y = fmaxf(acc.y + b.y, 0.f);
  ((float2*)out)[(long)i * 64 + lane] = r;
}

// ---------------- LSTM gates: gates[N,512] = X@Wih^T + Hs@Whh^T + (bih+bhh) ----------------
__launch_bounds__(256) __global__
void k_gates(const float* __restrict__ X, const float* __restrict__ Hs,
             const float* __restrict__ Wih, const float* __restrict__ Whh,
             const float* __restrict__ bih, const float* __restrict__ bhh,
             float* __restrict__ gates) {
  __shared__ float As[32][132];
  __shared__ float Bs[64][132];
  int t = threadIdx.x;
  int row0 = blockIdx.x * 32;
  int j0 = blockIdx.y * 64;
  int jg = t & 31;       // 32 j-groups of 2 cols
  int rg = t >> 5;       // 8 row-groups of 4 rows
  float acc[4][2] = {{0.f, 0.f}, {0.f, 0.f}, {0.f, 0.f}, {0.f, 0.f}};
  for (int ph = 0; ph < 2; ph++) {
    const float* Ap = ph ? Hs : X;
    const float* Bp = ph ? Whh : Wih;
    {
      int lr = t >> 3, lk = (t & 7) * 4;
      bool rok = (row0 + lr) < NN;
      const float* ar = Ap + (long)(row0 + lr) * 128;
#pragma unroll
      for (int i = 0; i < 4; i++) {
        float4 v = rok ? *(const float4*)(ar + lk + i * 32) : make_float4(0.f, 0.f, 0.f, 0.f);
        *(float4*)&As[lr][lk + i * 32] = v;
      }
    }
    {
      int br = t >> 2, bk = (t & 3) * 4;
      const float* brp = Bp + (long)(j0 + br) * 128;
#pragma unroll
      for (int i = 0; i < 8; i++) {
        float4 v = *(const float4*)(brp + bk + i * 16);
        *(float4*)&Bs[br][bk + i * 16] = v;
      }
    }
    __syncthreads();
    for (int k = 0; k < 128; k += 4) {
      float4 a[4];
#pragma unroll
      for (int r = 0; r < 4; r++) a[r] = *(float4*)&As[rg * 4 + r][k];
      float4 b0 = *(float4*)&Bs[jg * 2][k];
      float4 b1 = *(float4*)&Bs[jg * 2 + 1][k];
#pragma unroll
      for (int r = 0; r < 4; r++) {
        acc[r][0] += a[r].x * b0.x + a[r].y * b0.y + a[r].z * b0.z + a[r].w * b0.w;
        acc[r][1] += a[r].x * b1.x + a[r].y * b1.y + a[r].z * b1.z + a[r].w * b1.w;
      }
    }
    __syncthreads();
  }
  int j = j0 + jg * 2;
  float bb0 = bih[j] + bhh[j];
  float bb1 = bih[j + 1] + bhh[j + 1];
#pragma unroll
  for (int r = 0; r < 4; r++) {
    int row = row0 + rg * 4 + r;
    if (row < NN) {
      float2 o;
      o.x = acc[r][0] + bb0;
      o.y = acc[r][1] + bb1;
      *(float2*)&gates[(long)row * 512 + j] = o;
    }
  }
}

// ---------------- LSTM elementwise update ----------------
__global__ void k_lstm_ew(const float* __restrict__ gates, float* __restrict__ c,
                          float* __restrict__ hout) {
  long idx = (long)blockIdx.x * blockDim.x + threadIdx.x;
  if (idx >= (long)NN * 128) return;
  long n = idx >> 7;
  int j = (int)(idx & 127);
  const float* g = gates + n * 512;
  float xi = g[j], xf = g[128 + j], xg = g[256 + j], xo = g[384 + j];
  float si = 1.f / (1.f + expf(-xi));
  float sf = 1.f / (1.f + expf(-xf));
  float so = 1.f / (1.f + expf(-xo));
  float tg = tanhf(xg);
  float cn = sf * c[idx] + si * tg;
  c[idx] = cn;
  hout[idx] = so * tanhf(cn);
}

// ---------------- launcher ----------------
extern "C" void kernel_launch(void* const* d_in, const int* in_sizes, int n_in,
                              void* d_out, int out_size, void* d_ws, size_t ws_size,
                              hipStream_t stream) {
  const float* feats = (const float*)d_in[0];   // [T,N,128]
  const int*   edges = (const int*)d_in[1];     // [T,2,E]
  const float* W1    = (const float*)d_in[2];
  const float* b1    = (const float*)d_in[3];
  const float* W2    = (const float*)d_in[4];
  const float* b2    = (const float*)d_in[5];
  const float* Wih   = (const float*)d_in[6];   // [512,128]
  const float* Whh   = (const float*)d_in[7];
  const float* bih   = (const float*)d_in[8];
  const float* bhh   = (const float*)d_in[9];
  float* out = (float*)d_out;

  char* w = (char*)d_ws;
  auto alloc = [&](size_t bytes) {
    char* p = w;
    w += (bytes + 255) & ~(size_t)255;
    return p;
  };

  // region0: LSTM-phase gates buffer overlays GCN-phase scratch (disjoint live ranges)
  char* region0 = alloc((size_t)NN * 512 * 4);            // 102.4 MB
  float* gates  = (float*)region0;
  float* bufH   = (float*)region0;                        // 25.6 MB
  int*   csr    = (int*)(region0 + (size_t)NN * 128 * 4); // 6.4 MB
  int*   deg    = (int*)(region0 + (size_t)NN * 128 * 4 + (size_t)EE * 4);
  int*   rs     = deg + NN;                               // N+1 entries
  int*   cursor = rs + NN + 1;

  float* bufX   = (float*)alloc((size_t)NN * 128 * 4);    // emb_t
  float* hstate = (float*)alloc((size_t)NN * 128 * 4);
  float* cstate = (float*)alloc((size_t)NN * 128 * 4);    // contiguous after hstate
  float* dinv   = (float*)alloc((size_t)NN * 4);
  int*   bsum   = (int*)alloc(512);

  // zero h and c (contiguous, both multiples of 256B)
  {
    long n4 = (long)NN * 128 * 2 / 4;
    k_zero4<<<(int)((n4 + 255) / 256), 256, 0, stream>>>((float4*)hstate, n4);
  }

  int gblk = (NN + 31) / 32;   // 1563
  for (int t = 0; t < TT; t++) {
    const int* erow = edges + (size_t)t * 2 * EE;
    const int* ecol = erow + EE;
    const float* xt = feats + (size_t)t * NN * 128;

    // CSR by dest + dinv
    k_zeroi<<<(NN + 255) / 256, 256, 0, stream>>>(deg, NN);
    k_count<<<EE / 256, 256, 0, stream>>>(erow, deg);
    k_scan1<<<NBLK, SCAN_B, 0, stream>>>(deg, rs, bsum);
    k_scan2<<<1, 128, 0, stream>>>(bsum);
    k_scan3<<<(NN + 255) / 256, 256, 0, stream>>>(rs, bsum, deg, dinv, cursor);
    k_scatter<<<EE / 256, 256, 0, stream>>>(erow, ecol, cursor, csr);

    // GCN layer 1
    k_gemm_nn<<<gblk, 256, 0, stream>>>(xt, W1, bufH);
    k_agg<<<(NN + 3) / 4, 256, 0, stream>>>(bufH, dinv, rs, csr, b1, bufX);
    // GCN layer 2
    k_gemm_nn<<<gblk, 256, 0, stream>>>(bufX, W2, bufH);
    k_agg<<<(NN + 3) / 4, 256, 0, stream>>>(bufH, dinv, rs, csr, b2, bufX);

    // LSTM step (bufX = emb_t)
    dim3 gg(gblk, 8);
    k_gates<<<gg, 256, 0, stream>>>(bufX, hstate, Wih, Whh, bih, bhh, gates);
    float* hout = (t == TT - 1) ? out : hstate;
    k_lstm_ew<<<(int)(((long)NN * 128 + 255) / 256), 256, 0, stream>>>(gates, cstate, hout);
  }
}

// Round 5
// 5558.343 us; speedup vs baseline: 1.1661x; 1.1661x over previous
//
#include <hip/hip_runtime.h>
#include <hip/hip_bf16.h>

#define NN 50000
#define TT 8
#define EE 1600000

constexpr int SCAN_B = 512;
constexpr int NBLK = (NN + SCAN_B - 1) / SCAN_B; // 98

typedef __attribute__((ext_vector_type(8))) short bf16x8;
typedef __attribute__((ext_vector_type(4))) float f32x4;

__device__ inline unsigned short f2bf(float f) {
  unsigned int u = __float_as_uint(f);
  u += 0x7FFFu + ((u >> 16) & 1u);   // round-to-nearest-even
  return (unsigned short)(u >> 16);
}
__device__ inline float bf2f(unsigned short h) {
  return __uint_as_float(((unsigned int)h) << 16);
}

// ---------------- utility kernels ----------------
__global__ void k_zero4(float4* p, long n4) {
  long i = (long)blockIdx.x * blockDim.x + threadIdx.x;
  if (i < n4) p[i] = make_float4(0.f, 0.f, 0.f, 0.f);
}

__global__ void k_zeroi(int* p, int n) {
  int i = blockIdx.x * blockDim.x + threadIdx.x;
  if (i < n) p[i] = 0;
}

// ---------------- weight prep: split-bf16 + transpose + bias sum ----------------
__global__ void k_prep(const float* __restrict__ Wih, const float* __restrict__ Whh,
                       const float* __restrict__ W1, const float* __restrict__ W2,
                       const float* __restrict__ bih, const float* __restrict__ bhh,
                       unsigned short* WihH, unsigned short* WihL,
                       unsigned short* WhhH, unsigned short* WhhL,
                       unsigned short* W1tH, unsigned short* W1tL,
                       unsigned short* W2tH, unsigned short* W2tL, float* bsum) {
  int i = blockIdx.x * 256 + threadIdx.x;
  if (i < 512 * 128) {
    float v = Wih[i];
    unsigned short h = f2bf(v);
    WihH[i] = h; WihL[i] = f2bf(v - bf2f(h));
    v = Whh[i];
    h = f2bf(v);
    WhhH[i] = h; WhhL[i] = f2bf(v - bf2f(h));
  }
  if (i < 128 * 128) {
    int n = i >> 7, k = i & 127;
    float v = W1[(long)k * 128 + n];          // transpose: Wt[n][k] = W[k][n]
    unsigned short h = f2bf(v);
    W1tH[i] = h; W1tL[i] = f2bf(v - bf2f(h));
    v = W2[(long)k * 128 + n];
    h = f2bf(v);
    W2tH[i] = h; W2tL[i] = f2bf(v - bf2f(h));
  }
  if (i < 512) bsum[i] = bih[i] + bhh[i];
}

// ---------------- CSR build ----------------
__global__ void k_count(const int* __restrict__ row, int* __restrict__ deg) {
  int e = blockIdx.x * blockDim.x + threadIdx.x;
  if (e < EE) atomicAdd(&deg[row[e]], 1);
}

__global__ void k_scan1(const int* __restrict__ deg, int* __restrict__ rs, int* __restrict__ bsum) {
  __shared__ int s[SCAN_B];
  int t = threadIdx.x;
  int i = blockIdx.x * SCAN_B + t;
  int v = (i < NN) ? deg[i] : 0;
  s[t] = v;
  __syncthreads();
  for (int off = 1; off < SCAN_B; off <<= 1) {
    int add = (t >= off) ? s[t - off] : 0;
    __syncthreads();
    s[t] += add;
    __syncthreads();
  }
  if (i < NN) rs[i] = s[t] - v;
  if (t == SCAN_B - 1) bsum[blockIdx.x] = s[t];
}

__global__ void k_scan2(int* __restrict__ bsum) {
  __shared__ int s[128];
  int t = threadIdx.x;
  int v = (t < NBLK) ? bsum[t] : 0;
  s[t] = v;
  __syncthreads();
  for (int off = 1; off < 128; off <<= 1) {
    int add = (t >= off) ? s[t - off] : 0;
    __syncthreads();
    s[t] += add;
    __syncthreads();
  }
  if (t < NBLK) bsum[t] = s[t] - v;
}

__global__ void k_scan3(int* __restrict__ rs, const int* __restrict__ bsum, const int* __restrict__ deg,
                        float* __restrict__ dinv, int* __restrict__ cursor) {
  int i = blockIdx.x * blockDim.x + threadIdx.x;
  if (i < NN) {
    int v = rs[i] + bsum[i / SCAN_B];
    rs[i] = v;
    cursor[i] = v;
    dinv[i] = rsqrtf((float)(deg[i] + 1));
  }
  if (i == 0) rs[NN] = EE;
}

__global__ void k_scatter(const int* __restrict__ row, const int* __restrict__ col,
                          int* __restrict__ cursor, int* __restrict__ csr) {
  int e = blockIdx.x * blockDim.x + threadIdx.x;
  if (e < EE) {
    int r = row[e];
    int p = atomicAdd(&cursor[r], 1);
    csr[p] = col[e];
  }
}

#define MF(a, b, c) c = __builtin_amdgcn_mfma_f32_16x16x32_bf16(a, b, c, 0, 0, 0)

// ---------------- MFMA GEMM: C[N,128] = A[N,128] @ Wt^T (Wt[n][k] hi/lo bf16) ----------------
// AMODE 0: A fp32 (convert in-register); AMODE 1: A given as hi/lo bf16 buffers.
template <int AMODE>
__launch_bounds__(256) __global__
void k_gemm_mfma(const float* __restrict__ Af,
                 const unsigned short* __restrict__ Ahb, const unsigned short* __restrict__ Alb,
                 const unsigned short* __restrict__ BtH, const unsigned short* __restrict__ BtL,
                 float* __restrict__ C) {
  int tid = threadIdx.x;
  int wv = tid >> 6;
  int lane = tid & 63;
  int rA = lane & 15;
  int kg = lane >> 4;
  int m0 = blockIdx.x * 128 + wv * 32;
  int j0 = blockIdx.y * 32;
  long ar0 = min(m0 + rA, NN - 1);
  long ar1 = min(m0 + 16 + rA, NN - 1);
  long br0 = j0 + rA;
  long br1 = br0 + 16;
  f32x4 acc00 = {0.f, 0.f, 0.f, 0.f}, acc01 = acc00, acc10 = acc00, acc11 = acc00;
#pragma unroll
  for (int k0 = 0; k0 < 128; k0 += 32) {
    long ks = k0 + kg * 8;
    bf16x8 a0h, a0l, a1h, a1l;
    if constexpr (AMODE == 0) {
      float4 u0 = *(const float4*)(Af + ar0 * 128 + ks);
      float4 u1 = *(const float4*)(Af + ar0 * 128 + ks + 4);
      float4 u2 = *(const float4*)(Af + ar1 * 128 + ks);
      float4 u3 = *(const float4*)(Af + ar1 * 128 + ks + 4);
      float va[8] = {u0.x, u0.y, u0.z, u0.w, u1.x, u1.y, u1.z, u1.w};
      float vb[8] = {u2.x, u2.y, u2.z, u2.w, u3.x, u3.y, u3.z, u3.w};
#pragma unroll
      for (int e = 0; e < 8; e++) {
        unsigned short h = f2bf(va[e]);
        a0h[e] = (short)h; a0l[e] = (short)f2bf(va[e] - bf2f(h));
        unsigned short h2 = f2bf(vb[e]);
        a1h[e] = (short)h2; a1l[e] = (short)f2bf(vb[e] - bf2f(h2));
      }
    } else {
      a0h = *(const bf16x8*)(Ahb + ar0 * 128 + ks);
      a0l = *(const bf16x8*)(Alb + ar0 * 128 + ks);
      a1h = *(const bf16x8*)(Ahb + ar1 * 128 + ks);
      a1l = *(const bf16x8*)(Alb + ar1 * 128 + ks);
    }
    bf16x8 b0h = *(const bf16x8*)(BtH + br0 * 128 + ks);
    bf16x8 b0l = *(const bf16x8*)(BtL + br0 * 128 + ks);
    bf16x8 b1h = *(const bf16x8*)(BtH + br1 * 128 + ks);
    bf16x8 b1l = *(const bf16x8*)(BtL + br1 * 128 + ks);
    MF(a0l, b0h, acc00); MF(a0h, b0l, acc00); MF(a0h, b0h, acc00);
    MF(a0l, b1h, acc01); MF(a0h, b1l, acc01); MF(a0h, b1h, acc01);
    MF(a1l, b0h, acc10); MF(a1h, b0l, acc10); MF(a1h, b0h, acc10);
    MF(a1l, b1h, acc11); MF(a1h, b1l, acc11); MF(a1h, b1h, acc11);
  }
#pragma unroll
  for (int r = 0; r < 4; r++) {
    int row0 = m0 + kg * 4 + r;        // C/D frag: col=lane&15, row=(lane>>4)*4+reg
    int row1 = row0 + 16;
    if (row0 < NN) {
      C[(long)row0 * 128 + j0 + rA] = acc00[r];
      C[(long)row0 * 128 + j0 + 16 + rA] = acc01[r];
    }
    if (row1 < NN) {
      C[(long)row1 * 128 + j0 + rA] = acc10[r];
      C[(long)row1 * 128 + j0 + 16 + rA] = acc11[r];
    }
  }
}

// ---------------- GCN aggregation: 32 lanes per node, float4; emits hi/lo bf16 ----------------
__launch_bounds__(256) __global__
void k_agg(const float* __restrict__ Hm, const float* __restrict__ dinv,
           const int* __restrict__ rs, const int* __restrict__ csr,
           const float* __restrict__ bias,
           unsigned short* __restrict__ outH, unsigned short* __restrict__ outL) {
  int i = blockIdx.x * 8 + (threadIdx.x >> 5);
  int lane = threadIdx.x & 31;
  if (i >= NN) return;
  float di = dinv[i];
  const float4* H4 = (const float4*)Hm;
  float4 a = H4[(long)i * 32 + lane];
  float sw = di * di;
  float4 acc = {a.x * sw, a.y * sw, a.z * sw, a.w * sw};
  int e0 = rs[i], e1 = rs[i + 1];
  int e = e0;
  for (; e + 2 <= e1; e += 2) {
    int c0 = csr[e], c1 = csr[e + 1];
    float w0 = di * dinv[c0], w1 = di * dinv[c1];
    float4 v0 = H4[(long)c0 * 32 + lane];
    float4 v1 = H4[(long)c1 * 32 + lane];
    acc.x += w0 * v0.x + w1 * v1.x;
    acc.y += w0 * v0.y + w1 * v1.y;
    acc.z += w0 * v0.z + w1 * v1.z;
    acc.w += w0 * v0.w + w1 * v1.w;
  }
  if (e < e1) {
    int c0 = csr[e];
    float w0 = di * dinv[c0];
    float4 v0 = H4[(long)c0 * 32 + lane];
    acc.x += w0 * v0.x; acc.y += w0 * v0.y; acc.z += w0 * v0.z; acc.w += w0 * v0.w;
  }
  float4 b = ((const float4*)bias)[lane];
  float4 v;
  v.x = fmaxf(acc.x + b.x, 0.f);
  v.y = fmaxf(acc.y + b.y, 0.f);
  v.z = fmaxf(acc.z + b.z, 0.f);
  v.w = fmaxf(acc.w + b.w, 0.f);
  ushort4 hh, hl;
  unsigned short h;
  h = f2bf(v.x); hh.x = h; hl.x = f2bf(v.x - bf2f(h));
  h = f2bf(v.y); hh.y = h; hl.y = f2bf(v.y - bf2f(h));
  h = f2bf(v.z); hh.z = h; hl.z = f2bf(v.z - bf2f(h));
  h = f2bf(v.w); hh.w = h; hl.w = f2bf(v.w - bf2f(h));
  ((ushort4*)outH)[(long)i * 32 + lane] = hh;
  ((ushort4*)outL)[(long)i * 32 + lane] = hl;
}

// ---------------- fused LSTM step: gates GEMM (MFMA split-bf16) + elementwise ----------------
// Block: 32 rows x 32 h-cols; wave w computes gate w's 32x32 tile; LDS exchange; epilogue.
__launch_bounds__(256) __global__
void k_gates_lstm(const unsigned short* __restrict__ Xh, const unsigned short* __restrict__ Xl,
                  const unsigned short* __restrict__ Hh, const unsigned short* __restrict__ Hl,
                  const unsigned short* __restrict__ WihH, const unsigned short* __restrict__ WihL,
                  const unsigned short* __restrict__ WhhH, const unsigned short* __restrict__ WhhL,
                  const float* __restrict__ bsum, float* __restrict__ cst,
                  unsigned short* __restrict__ HoH, unsigned short* __restrict__ HoL,
                  float* __restrict__ out, int last) {
  __shared__ float G[4][32][36];
  int tid = threadIdx.x;
  int wv = tid >> 6;                   // gate index (i,f,g,o)
  int lane = tid & 63;
  int rA = lane & 15;
  int kg = lane >> 4;
  int m0 = blockIdx.x * 32;
  int j0 = blockIdx.y * 32;
  long ar0 = min(m0 + rA, NN - 1);
  long ar1 = min(m0 + 16 + rA, NN - 1);
  long br0 = wv * 128 + j0 + rA;
  long br1 = br0 + 16;
  f32x4 acc00 = {0.f, 0.f, 0.f, 0.f}, acc01 = acc00, acc10 = acc00, acc11 = acc00;

  auto kloop = [&](const unsigned short* Ah, const unsigned short* Al,
                   const unsigned short* Bh, const unsigned short* Bl) {
#pragma unroll
    for (int k0 = 0; k0 < 128; k0 += 32) {
      long ks = k0 + kg * 8;
      bf16x8 a0h = *(const bf16x8*)(Ah + ar0 * 128 + ks);
      bf16x8 a0l = *(const bf16x8*)(Al + ar0 * 128 + ks);
      bf16x8 a1h = *(const bf16x8*)(Ah + ar1 * 128 + ks);
      bf16x8 a1l = *(const bf16x8*)(Al + ar1 * 128 + ks);
      bf16x8 b0h = *(const bf16x8*)(Bh + br0 * 128 + ks);
      bf16x8 b0l = *(const bf16x8*)(Bl + br0 * 128 + ks);
      bf16x8 b1h = *(const bf16x8*)(Bh + br1 * 128 + ks);
      bf16x8 b1l = *(const bf16x8*)(Bl + br1 * 128 + ks);
      MF(a0l, b0h, acc00); MF(a0h, b0l, acc00); MF(a0h, b0h, acc00);
      MF(a0l, b1h, acc01); MF(a0h, b1l, acc01); MF(a0h, b1h, acc01);
      MF(a1l, b0h, acc10); MF(a1h, b0l, acc10); MF(a1h, b0h, acc10);
      MF(a1l, b1h, acc11); MF(a1h, b1l, acc11); MF(a1h, b1h, acc11);
    }
  };
  kloop(Xh, Xl, WihH, WihL);
  kloop(Hh, Hl, WhhH, WhhL);

#pragma unroll
  for (int r = 0; r < 4; r++) {
    G[wv][kg * 4 + r][rA] = acc00[r];
    G[wv][kg * 4 + r][16 + rA] = acc01[r];
    G[wv][16 + kg * 4 + r][rA] = acc10[r];
    G[wv][16 + kg * 4 + r][16 + rA] = acc11[r];
  }
  __syncthreads();

  int pr = tid >> 3;
  int pc = (tid & 7) * 4;
  int row = m0 + pr;
  if (row < NN) {
    float4 vgi = *(float4*)&G[0][pr][pc];
    float4 vgf = *(float4*)&G[1][pr][pc];
    float4 vgg = *(float4*)&G[2][pr][pc];
    float4 vgo = *(float4*)&G[3][pr][pc];
    float4 bsi = *(const float4*)(bsum + j0 + pc);
    float4 bsf = *(const float4*)(bsum + 128 + j0 + pc);
    float4 bsg = *(const float4*)(bsum + 256 + j0 + pc);
    float4 bso = *(const float4*)(bsum + 384 + j0 + pc);
    long off = (long)row * 128 + j0 + pc;
    float4 co = *(const float4*)(cst + off);
    float4 cn, hv;
#define LCOMP(X)                                           \
  {                                                        \
    float iv = 1.f / (1.f + expf(-(vgi.X + bsi.X)));       \
    float fv = 1.f / (1.f + expf(-(vgf.X + bsf.X)));       \
    float gv = tanhf(vgg.X + bsg.X);                       \
    float ov = 1.f / (1.f + expf(-(vgo.X + bso.X)));       \
    float c2 = fv * co.X + iv * gv;                        \
    cn.X = c2;                                             \
    hv.X = ov * tanhf(c2);                                 \
  }
    LCOMP(x) LCOMP(y) LCOMP(z) LCOMP(w)
#undef LCOMP
    *(float4*)(cst + off) = cn;
    ushort4 hh, hl;
    unsigned short h;
    h = f2bf(hv.x); hh.x = h; hl.x = f2bf(hv.x - bf2f(h));
    h = f2bf(hv.y); hh.y = h; hl.y = f2bf(hv.y - bf2f(h));
    h = f2bf(hv.z); hh.z = h; hl.z = f2bf(hv.z - bf2f(h));
    h = f2bf(hv.w); hh.w = h; hl.w = f2bf(hv.w - bf2f(h));
    *(ushort4*)(HoH + off) = hh;
    *(ushort4*)(HoL + off) = hl;
    if (last) *(float4*)(out + off) = hv;
  }
}

// ---------------- launcher ----------------
extern "C" void kernel_launch(void* const* d_in, const int* in_sizes, int n_in,
                              void* d_out, int out_size, void* d_ws, size_t ws_size,
                              hipStream_t stream) {
  const float* feats = (const float*)d_in[0];   // [T,N,128]
  const int*   edges = (const int*)d_in[1];     // [T,2,E]
  const float* W1    = (const float*)d_in[2];
  const float* b1    = (const float*)d_in[3];
  const float* W2    = (const float*)d_in[4];
  const float* b2    = (const float*)d_in[5];
  const float* Wih   = (const float*)d_in[6];   // [512,128]
  const float* Whh   = (const float*)d_in[7];
  const float* bih   = (const float*)d_in[8];
  const float* bhh   = (const float*)d_in[9];
  float* out = (float*)d_out;

  char* w = (char*)d_ws;
  auto alloc = [&](size_t bytes) {
    char* p = w;
    w += (bytes + 255) & ~(size_t)255;
    return p;
  };

  const size_t NB2 = (size_t)NN * 128 * 2;   // bf16 plane, 12.8 MB (multiple of 256)
  const size_t NB4 = (size_t)NN * 128 * 4;   // fp32 plane, 25.6 MB

  int*   csr    = (int*)alloc((size_t)EE * 4);
  int*   deg    = (int*)alloc((size_t)NN * 4);
  int*   rs     = (int*)alloc((size_t)(NN + 1) * 4);
  int*   cursor = (int*)alloc((size_t)NN * 4);
  float* dinv   = (float*)alloc((size_t)NN * 4);
  int*   bsumP  = (int*)alloc(512);

  float* bufH  = (float*)alloc(NB4);
  unsigned short* bufXh = (unsigned short*)alloc(NB2);
  unsigned short* bufXl = (unsigned short*)alloc(NB2);
  unsigned short* Xembh = (unsigned short*)alloc(NB2);
  unsigned short* Xembl = (unsigned short*)alloc(NB2);

  // zero region: HsA hi/lo + cstate, contiguous 51.2 MB
  char* zr = alloc(NB2 + NB2 + NB4);
  unsigned short* HsAh = (unsigned short*)zr;
  unsigned short* HsAl = (unsigned short*)(zr + NB2);
  float* cstate = (float*)(zr + 2 * NB2);

  unsigned short* HsBh = (unsigned short*)alloc(NB2);
  unsigned short* HsBl = (unsigned short*)alloc(NB2);

  unsigned short* WihH = (unsigned short*)alloc(512 * 128 * 2);
  unsigned short* WihL = (unsigned short*)alloc(512 * 128 * 2);
  unsigned short* WhhH = (unsigned short*)alloc(512 * 128 * 2);
  unsigned short* WhhL = (unsigned short*)alloc(512 * 128 * 2);
  unsigned short* W1tH = (unsigned short*)alloc(128 * 128 * 2);
  unsigned short* W1tL = (unsigned short*)alloc(128 * 128 * 2);
  unsigned short* W2tH = (unsigned short*)alloc(128 * 128 * 2);
  unsigned short* W2tL = (unsigned short*)alloc(128 * 128 * 2);
  float* bsum = (float*)alloc(512 * 4);

  k_prep<<<256, 256, 0, stream>>>(Wih, Whh, W1, W2, bih, bhh,
                                  WihH, WihL, WhhH, WhhL, W1tH, W1tL, W2tH, W2tL, bsum);
  {
    long n4 = (long)(2 * NB2 + NB4) / 16;    // 3,200,000 float4s
    k_zero4<<<(int)((n4 + 255) / 256), 256, 0, stream>>>((float4*)zr, n4);
  }

  for (int t = 0; t < TT; t++) {
    const int* erow = edges + (size_t)t * 2 * EE;
    const int* ecol = erow + EE;
    const float* xt = feats + (size_t)t * NN * 128;

    // CSR by dest + dinv
    k_zeroi<<<(NN + 255) / 256, 256, 0, stream>>>(deg, NN);
    k_count<<<EE / 256, 256, 0, stream>>>(erow, deg);
    k_scan1<<<NBLK, SCAN_B, 0, stream>>>(deg, rs, bsumP);
    k_scan2<<<1, 128, 0, stream>>>(bsumP);
    k_scan3<<<(NN + 255) / 256, 256, 0, stream>>>(rs, bsumP, deg, dinv, cursor);
    k_scatter<<<EE / 256, 256, 0, stream>>>(erow, ecol, cursor, csr);

    // GCN layer 1: feats(fp32) @ W1 -> bufH; aggregate -> bufX hi/lo
    k_gemm_mfma<0><<<dim3(391, 4), 256, 0, stream>>>(xt, nullptr, nullptr, W1tH, W1tL, bufH);
    k_agg<<<NN / 8, 256, 0, stream>>>(bufH, dinv, rs, csr, b1, bufXh, bufXl);
    // GCN layer 2: bufX(hi/lo) @ W2 -> bufH; aggregate -> Xemb hi/lo
    k_gemm_mfma<1><<<dim3(391, 4), 256, 0, stream>>>(nullptr, bufXh, bufXl, W2tH, W2tL, bufH);
    k_agg<<<NN / 8, 256, 0, stream>>>(bufH, dinv, rs, csr, b2, Xembh, Xembl);

    // fused LSTM step (h ping-pong: even t reads A writes B; odd reads B writes A)
    const unsigned short *rH, *rL;
    unsigned short *wH, *wL;
    if ((t & 1) == 0) { rH = HsAh; rL = HsAl; wH = HsBh; wL = HsBl; }
    else              { rH = HsBh; rL = HsBl; wH = HsAh; wL = HsAl; }
    k_gates_lstm<<<dim3(1563, 4), 256, 0, stream>>>(
        Xembh, Xembl, rH, rL, WihH, WihL, WhhH, WhhL, bsum, cstate,
        wH, wL, out, (t == TT - 1) ? 1 : 0);
  }
}

// Round 6
// 5081.671 us; speedup vs baseline: 1.2754x; 1.0938x over previous
//
#include <hip/hip_runtime.h>
#include <hip/hip_bf16.h>

#define NN 50000
#define TT 8
#define EE 1600000

constexpr int SCAN_B = 512;
constexpr int NBLK = (NN + SCAN_B - 1) / SCAN_B; // 98

typedef __attribute__((ext_vector_type(8))) short bf16x8;
typedef __attribute__((ext_vector_type(4))) float f32x4;

__device__ inline unsigned short f2bf(float f) {
  unsigned int u = __float_as_uint(f);
  u += 0x7FFFu + ((u >> 16) & 1u);   // round-to-nearest-even
  return (unsigned short)(u >> 16);
}
__device__ inline float bf2f(unsigned short h) {
  return __uint_as_float(((unsigned int)h) << 16);
}

// ---------------- utility kernels ----------------
__global__ void k_zero4(float4* p, long n4) {
  long i = (long)blockIdx.x * blockDim.x + threadIdx.x;
  if (i < n4) p[i] = make_float4(0.f, 0.f, 0.f, 0.f);
}

__global__ void k_zeroi(int* p, int n) {
  int i = blockIdx.x * blockDim.x + threadIdx.x;
  if (i < n) p[i] = 0;
}

// ---------------- weight prep: split-bf16 + transpose + bias sum ----------------
__global__ void k_prep(const float* __restrict__ Wih, const float* __restrict__ Whh,
                       const float* __restrict__ W1, const float* __restrict__ W2,
                       const float* __restrict__ bih, const float* __restrict__ bhh,
                       unsigned short* WihH, unsigned short* WihL,
                       unsigned short* WhhH, unsigned short* WhhL,
                       unsigned short* W1tH, unsigned short* W1tL,
                       unsigned short* W2tH, unsigned short* W2tL, float* bsum) {
  int i = blockIdx.x * 256 + threadIdx.x;
  if (i < 512 * 128) {
    float v = Wih[i];
    unsigned short h = f2bf(v);
    WihH[i] = h; WihL[i] = f2bf(v - bf2f(h));
    v = Whh[i];
    h = f2bf(v);
    WhhH[i] = h; WhhL[i] = f2bf(v - bf2f(h));
  }
  if (i < 128 * 128) {
    int n = i >> 7, k = i & 127;
    float v = W1[(long)k * 128 + n];          // transpose: Wt[n][k] = W[k][n]
    unsigned short h = f2bf(v);
    W1tH[i] = h; W1tL[i] = f2bf(v - bf2f(h));
    v = W2[(long)k * 128 + n];
    h = f2bf(v);
    W2tH[i] = h; W2tL[i] = f2bf(v - bf2f(h));
  }
  if (i < 512) bsum[i] = bih[i] + bhh[i];
}

// ---------------- CSR build ----------------
__global__ void k_count(const int* __restrict__ row, int* __restrict__ deg) {
  int e = blockIdx.x * blockDim.x + threadIdx.x;
  if (e < EE) atomicAdd(&deg[row[e]], 1);
}

__global__ void k_scan1(const int* __restrict__ deg, int* __restrict__ rs, int* __restrict__ bsum) {
  __shared__ int s[SCAN_B];
  int t = threadIdx.x;
  int i = blockIdx.x * SCAN_B + t;
  int v = (i < NN) ? deg[i] : 0;
  s[t] = v;
  __syncthreads();
  for (int off = 1; off < SCAN_B; off <<= 1) {
    int add = (t >= off) ? s[t - off] : 0;
    __syncthreads();
    s[t] += add;
    __syncthreads();
  }
  if (i < NN) rs[i] = s[t] - v;
  if (t == SCAN_B - 1) bsum[blockIdx.x] = s[t];
}

__global__ void k_scan2(int* __restrict__ bsum) {
  __shared__ int s[128];
  int t = threadIdx.x;
  int v = (t < NBLK) ? bsum[t] : 0;
  s[t] = v;
  __syncthreads();
  for (int off = 1; off < 128; off <<= 1) {
    int add = (t >= off) ? s[t - off] : 0;
    __syncthreads();
    s[t] += add;
    __syncthreads();
  }
  if (t < NBLK) bsum[t] = s[t] - v;
}

__global__ void k_scan3(int* __restrict__ rs, const int* __restrict__ bsum, const int* __restrict__ deg,
                        float* __restrict__ dinv, int* __restrict__ cursor) {
  int i = blockIdx.x * blockDim.x + threadIdx.x;
  if (i < NN) {
    int v = rs[i] + bsum[i / SCAN_B];
    rs[i] = v;
    cursor[i] = v;
    dinv[i] = rsqrtf((float)(deg[i] + 1));
  }
  if (i == 0) rs[NN] = EE;
}

__global__ void k_scatter(const int* __restrict__ row, const int* __restrict__ col,
                          int* __restrict__ cursor, int* __restrict__ csr) {
  int e = blockIdx.x * blockDim.x + threadIdx.x;
  if (e < EE) {
    int r = row[e];
    int p = atomicAdd(&cursor[r], 1);
    csr[p] = col[e];
  }
}

#define MF(a, b, c) c = __builtin_amdgcn_mfma_f32_16x16x32_bf16(a, b, c, 0, 0, 0)

// ---------------- MFMA GEMM: C[N,128] = dinv * (A[N,128] @ Wt^T) ----------------
// 1D grid; A frags held in registers across all 4 j-tiles (no A re-fetch).
// AMODE 0: A fp32 (convert in-register); AMODE 1: A as hi/lo bf16 buffers.
template <int AMODE>
__launch_bounds__(256) __global__
void k_gemm_mfma(const float* __restrict__ Af,
                 const unsigned short* __restrict__ Ahb, const unsigned short* __restrict__ Alb,
                 const unsigned short* __restrict__ BtH, const unsigned short* __restrict__ BtL,
                 const float* __restrict__ dinv, float* __restrict__ C) {
  int tid = threadIdx.x;
  int wv = tid >> 6;
  int lane = tid & 63;
  int rA = lane & 15;
  int kg = lane >> 4;
  int m0 = blockIdx.x * 128 + wv * 32;
  long ar0 = min(m0 + rA, NN - 1);
  long ar1 = min(m0 + 16 + rA, NN - 1);

  bf16x8 a[4][2][2];   // [k0][rowtile][hi/lo]
#pragma unroll
  for (int k0 = 0; k0 < 4; k0++) {
    long ks = k0 * 32 + kg * 8;
    if constexpr (AMODE == 0) {
      float4 u0 = *(const float4*)(Af + ar0 * 128 + ks);
      float4 u1 = *(const float4*)(Af + ar0 * 128 + ks + 4);
      float4 u2 = *(const float4*)(Af + ar1 * 128 + ks);
      float4 u3 = *(const float4*)(Af + ar1 * 128 + ks + 4);
      float va[8] = {u0.x, u0.y, u0.z, u0.w, u1.x, u1.y, u1.z, u1.w};
      float vb[8] = {u2.x, u2.y, u2.z, u2.w, u3.x, u3.y, u3.z, u3.w};
#pragma unroll
      for (int e = 0; e < 8; e++) {
        unsigned short h = f2bf(va[e]);
        a[k0][0][0][e] = (short)h; a[k0][0][1][e] = (short)f2bf(va[e] - bf2f(h));
        h = f2bf(vb[e]);
        a[k0][1][0][e] = (short)h; a[k0][1][1][e] = (short)f2bf(vb[e] - bf2f(h));
      }
    } else {
      a[k0][0][0] = *(const bf16x8*)(Ahb + ar0 * 128 + ks);
      a[k0][0][1] = *(const bf16x8*)(Alb + ar0 * 128 + ks);
      a[k0][1][0] = *(const bf16x8*)(Ahb + ar1 * 128 + ks);
      a[k0][1][1] = *(const bf16x8*)(Alb + ar1 * 128 + ks);
    }
  }

  f32x4 acc[4][4];   // [j][tile: r0c0, r0c1, r1c0, r1c1]
#pragma unroll
  for (int j = 0; j < 4; j++)
#pragma unroll
    for (int q = 0; q < 4; q++) acc[j][q] = (f32x4){0.f, 0.f, 0.f, 0.f};

#pragma unroll
  for (int k0 = 0; k0 < 4; k0++) {
    long ks = k0 * 32 + kg * 8;
#pragma unroll
    for (int j = 0; j < 4; j++) {
      long b0 = (long)(j * 32 + rA) * 128 + ks;
      long b1 = (long)(j * 32 + 16 + rA) * 128 + ks;
      bf16x8 b0h = *(const bf16x8*)(BtH + b0);
      bf16x8 b0l = *(const bf16x8*)(BtL + b0);
      bf16x8 b1h = *(const bf16x8*)(BtH + b1);
      bf16x8 b1l = *(const bf16x8*)(BtL + b1);
      MF(a[k0][0][1], b0h, acc[j][0]); MF(a[k0][0][0], b0l, acc[j][0]); MF(a[k0][0][0], b0h, acc[j][0]);
      MF(a[k0][0][1], b1h, acc[j][1]); MF(a[k0][0][0], b1l, acc[j][1]); MF(a[k0][0][0], b1h, acc[j][1]);
      MF(a[k0][1][1], b0h, acc[j][2]); MF(a[k0][1][0], b0l, acc[j][2]); MF(a[k0][1][0], b0h, acc[j][2]);
      MF(a[k0][1][1], b1h, acc[j][3]); MF(a[k0][1][0], b1l, acc[j][3]); MF(a[k0][1][0], b1h, acc[j][3]);
    }
  }

#pragma unroll
  for (int r = 0; r < 4; r++) {
    int row0 = m0 + kg * 4 + r;    // C/D frag: col=lane&15, row=(lane>>4)*4+reg
    int row1 = row0 + 16;
    if (row0 < NN) {
      float dv = dinv[row0];
#pragma unroll
      for (int j = 0; j < 4; j++) {
        C[(long)row0 * 128 + j * 32 + rA] = acc[j][0][r] * dv;
        C[(long)row0 * 128 + j * 32 + 16 + rA] = acc[j][1][r] * dv;
      }
    }
    if (row1 < NN) {
      float dv = dinv[row1];
#pragma unroll
      for (int j = 0; j < 4; j++) {
        C[(long)row1 * 128 + j * 32 + rA] = acc[j][2][r] * dv;
        C[(long)row1 * 128 + j * 32 + 16 + rA] = acc[j][3][r] * dv;
      }
    }
  }
}

// ---------------- GCN aggregation: rows pre-scaled by dinv; pure gather+add ----------------
__launch_bounds__(256) __global__
void k_agg(const float* __restrict__ Hs, const float* __restrict__ dinv,
           const int* __restrict__ rs, const int* __restrict__ csr,
           const float* __restrict__ bias,
           unsigned short* __restrict__ outH, unsigned short* __restrict__ outL) {
  int i = blockIdx.x * 8 + (threadIdx.x >> 5);
  int lane = threadIdx.x & 31;
  if (i >= NN) return;
  const float4* H4 = (const float4*)Hs;
  float4 acc = H4[(long)i * 32 + lane];    // self term: dinv_i * h_i (pre-scaled)
  int e0 = rs[i], e1 = rs[i + 1];
  int e = e0;
  for (; e + 4 <= e1; e += 4) {
    int c0 = csr[e], c1 = csr[e + 1], c2 = csr[e + 2], c3 = csr[e + 3];
    float4 v0 = H4[(long)c0 * 32 + lane];
    float4 v1 = H4[(long)c1 * 32 + lane];
    float4 v2 = H4[(long)c2 * 32 + lane];
    float4 v3 = H4[(long)c3 * 32 + lane];
    acc.x += v0.x + v1.x + v2.x + v3.x;
    acc.y += v0.y + v1.y + v2.y + v3.y;
    acc.z += v0.z + v1.z + v2.z + v3.z;
    acc.w += v0.w + v1.w + v2.w + v3.w;
  }
  for (; e < e1; e++) {
    int c0 = csr[e];
    float4 v0 = H4[(long)c0 * 32 + lane];
    acc.x += v0.x; acc.y += v0.y; acc.z += v0.z; acc.w += v0.w;
  }
  float di = dinv[i];
  float4 b = ((const float4*)bias)[lane];
  float4 v;
  v.x = fmaxf(di * acc.x + b.x, 0.f);
  v.y = fmaxf(di * acc.y + b.y, 0.f);
  v.z = fmaxf(di * acc.z + b.z, 0.f);
  v.w = fmaxf(di * acc.w + b.w, 0.f);
  ushort4 hh, hl;
  unsigned short h;
  h = f2bf(v.x); hh.x = h; hl.x = f2bf(v.x - bf2f(h));
  h = f2bf(v.y); hh.y = h; hl.y = f2bf(v.y - bf2f(h));
  h = f2bf(v.z); hh.z = h; hl.z = f2bf(v.z - bf2f(h));
  h = f2bf(v.w); hh.w = h; hl.w = f2bf(v.w - bf2f(h));
  ((ushort4*)outH)[(long)i * 32 + lane] = hh;
  ((ushort4*)outL)[(long)i * 32 + lane] = hl;
}

// ---------------- fused LSTM step: A-frags in regs, j-tile loop, epilogue per tile ----------------
__launch_bounds__(256) __global__
void k_gates_lstm(const unsigned short* __restrict__ Xh, const unsigned short* __restrict__ Xl,
                  const unsigned short* __restrict__ Hh, const unsigned short* __restrict__ Hl,
                  const unsigned short* __restrict__ WihH, const unsigned short* __restrict__ WihL,
                  const unsigned short* __restrict__ WhhH, const unsigned short* __restrict__ WhhL,
                  const float* __restrict__ bsum, float* __restrict__ cst,
                  unsigned short* __restrict__ HoH, unsigned short* __restrict__ HoL,
                  float* __restrict__ out, int last) {
  __shared__ float G[4][32][36];
  int tid = threadIdx.x;
  int wv = tid >> 6;                   // gate index (i,f,g,o)
  int lane = tid & 63;
  int rA = lane & 15;
  int kg = lane >> 4;
  int m0 = blockIdx.x * 32;
  long ar0 = min(m0 + rA, NN - 1);
  long ar1 = min(m0 + 16 + rA, NN - 1);

  bf16x8 xa[4][2][2], ha[4][2][2];   // [k0][rowtile][hi/lo] — held across all j
#pragma unroll
  for (int k0 = 0; k0 < 4; k0++) {
    long ks = k0 * 32 + kg * 8;
    xa[k0][0][0] = *(const bf16x8*)(Xh + ar0 * 128 + ks);
    xa[k0][0][1] = *(const bf16x8*)(Xl + ar0 * 128 + ks);
    xa[k0][1][0] = *(const bf16x8*)(Xh + ar1 * 128 + ks);
    xa[k0][1][1] = *(const bf16x8*)(Xl + ar1 * 128 + ks);
    ha[k0][0][0] = *(const bf16x8*)(Hh + ar0 * 128 + ks);
    ha[k0][0][1] = *(const bf16x8*)(Hl + ar0 * 128 + ks);
    ha[k0][1][0] = *(const bf16x8*)(Hh + ar1 * 128 + ks);
    ha[k0][1][1] = *(const bf16x8*)(Hl + ar1 * 128 + ks);
  }

  for (int j = 0; j < 4; j++) {
    f32x4 acc00 = {0.f, 0.f, 0.f, 0.f}, acc01 = acc00, acc10 = acc00, acc11 = acc00;
    long brb = (long)wv * 128 + j * 32;
#pragma unroll
    for (int k0 = 0; k0 < 4; k0++) {
      long ks = k0 * 32 + kg * 8;
      long b0 = (brb + rA) * 128 + ks, b1 = (brb + 16 + rA) * 128 + ks;
      bf16x8 b0h = *(const bf16x8*)(WihH + b0);
      bf16x8 b0l = *(const bf16x8*)(WihL + b0);
      bf16x8 b1h = *(const bf16x8*)(WihH + b1);
      bf16x8 b1l = *(const bf16x8*)(WihL + b1);
      MF(xa[k0][0][1], b0h, acc00); MF(xa[k0][0][0], b0l, acc00); MF(xa[k0][0][0], b0h, acc00);
      MF(xa[k0][0][1], b1h, acc01); MF(xa[k0][0][0], b1l, acc01); MF(xa[k0][0][0], b1h, acc01);
      MF(xa[k0][1][1], b0h, acc10); MF(xa[k0][1][0], b0l, acc10); MF(xa[k0][1][0], b0h, acc10);
      MF(xa[k0][1][1], b1h, acc11); MF(xa[k0][1][0], b1l, acc11); MF(xa[k0][1][0], b1h, acc11);
    }
#pragma unroll
    for (int k0 = 0; k0 < 4; k0++) {
      long ks = k0 * 32 + kg * 8;
      long b0 = (brb + rA) * 128 + ks, b1 = (brb + 16 + rA) * 128 + ks;
      bf16x8 b0h = *(const bf16x8*)(WhhH + b0);
      bf16x8 b0l = *(const bf16x8*)(WhhL + b0);
      bf16x8 b1h = *(const bf16x8*)(WhhH + b1);
      bf16x8 b1l = *(const bf16x8*)(WhhL + b1);
      MF(ha[k0][0][1], b0h, acc00); MF(ha[k0][0][0], b0l, acc00); MF(ha[k0][0][0], b0h, acc00);
      MF(ha[k0][0][1], b1h, acc01); MF(ha[k0][0][0], b1l, acc01); MF(ha[k0][0][0], b1h, acc01);
      MF(ha[k0][1][1], b0h, acc10); MF(ha[k0][1][0], b0l, acc10); MF(ha[k0][1][0], b0h, acc10);
      MF(ha[k0][1][1], b1h, acc11); MF(ha[k0][1][0], b1l, acc11); MF(ha[k0][1][0], b1h, acc11);
    }
#pragma unroll
    for (int r = 0; r < 4; r++) {
      G[wv][kg * 4 + r][rA] = acc00[r];
      G[wv][kg * 4 + r][16 + rA] = acc01[r];
      G[wv][16 + kg * 4 + r][rA] = acc10[r];
      G[wv][16 + kg * 4 + r][16 + rA] = acc11[r];
    }
    __syncthreads();
    {
      int pr = tid >> 3;
      int pc = (tid & 7) * 4;
      int row = m0 + pr;
      if (row < NN) {
        float4 vgi = *(float4*)&G[0][pr][pc];
        float4 vgf = *(float4*)&G[1][pr][pc];
        float4 vgg = *(float4*)&G[2][pr][pc];
        float4 vgo = *(float4*)&G[3][pr][pc];
        float4 bsi = *(const float4*)(bsum + j * 32 + pc);
        float4 bsf = *(const float4*)(bsum + 128 + j * 32 + pc);
        float4 bsg = *(const float4*)(bsum + 256 + j * 32 + pc);
        float4 bso = *(const float4*)(bsum + 384 + j * 32 + pc);
        long off = (long)row * 128 + j * 32 + pc;
        float4 co = *(const float4*)(cst + off);
        float4 cn, hv;
#define LCOMP(X)                                           \
  {                                                        \
    float iv = 1.f / (1.f + expf(-(vgi.X + bsi.X)));       \
    float fv = 1.f / (1.f + expf(-(vgf.X + bsf.X)));       \
    float gv = tanhf(vgg.X + bsg.X);                       \
    float ov = 1.f / (1.f + expf(-(vgo.X + bso.X)));       \
    float c2 = fv * co.X + iv * gv;                        \
    cn.X = c2;                                             \
    hv.X = ov * tanhf(c2);                                 \
  }
        LCOMP(x) LCOMP(y) LCOMP(z) LCOMP(w)
#undef LCOMP
        *(float4*)(cst + off) = cn;
        ushort4 hh, hl;
        unsigned short h;
        h = f2bf(hv.x); hh.x = h; hl.x = f2bf(hv.x - bf2f(h));
        h = f2bf(hv.y); hh.y = h; hl.y = f2bf(hv.y - bf2f(h));
        h = f2bf(hv.z); hh.z = h; hl.z = f2bf(hv.z - bf2f(h));
        h = f2bf(hv.w); hh.w = h; hl.w = f2bf(hv.w - bf2f(h));
        *(ushort4*)(HoH + off) = hh;
        *(ushort4*)(HoL + off) = hl;
        if (last) *(float4*)(out + off) = hv;
      }
    }
    __syncthreads();
  }
}

// ---------------- launcher ----------------
extern "C" void kernel_launch(void* const* d_in, const int* in_sizes, int n_in,
                              void* d_out, int out_size, void* d_ws, size_t ws_size,
                              hipStream_t stream) {
  const float* feats = (const float*)d_in[0];   // [T,N,128]
  const int*   edges = (const int*)d_in[1];     // [T,2,E]
  const float* W1    = (const float*)d_in[2];
  const float* b1    = (const float*)d_in[3];
  const float* W2    = (const float*)d_in[4];
  const float* b2    = (const float*)d_in[5];
  const float* Wih   = (const float*)d_in[6];   // [512,128]
  const float* Whh   = (const float*)d_in[7];
  const float* bih   = (const float*)d_in[8];
  const float* bhh   = (const float*)d_in[9];
  float* out = (float*)d_out;

  char* w = (char*)d_ws;
  auto alloc = [&](size_t bytes) {
    char* p = w;
    w += (bytes + 255) & ~(size_t)255;
    return p;
  };

  const size_t NB2 = (size_t)NN * 128 * 2;   // bf16 plane, 12.8 MB
  const size_t NB4 = (size_t)NN * 128 * 4;   // fp32 plane, 25.6 MB

  int*   csr    = (int*)alloc((size_t)EE * 4);
  int*   deg    = (int*)alloc((size_t)NN * 4);
  int*   rs     = (int*)alloc((size_t)(NN + 1) * 4);
  int*   cursor = (int*)alloc((size_t)NN * 4);
  float* dinv   = (float*)alloc((size_t)NN * 4);
  int*   bsumP  = (int*)alloc(512);

  float* bufH  = (float*)alloc(NB4);
  unsigned short* bufXh = (unsigned short*)alloc(NB2);
  unsigned short* bufXl = (unsigned short*)alloc(NB2);
  unsigned short* Xembh = (unsigned short*)alloc(NB2);
  unsigned short* Xembl = (unsigned short*)alloc(NB2);

  // zero region: HsA hi/lo + cstate, contiguous 51.2 MB
  char* zr = alloc(NB2 + NB2 + NB4);
  unsigned short* HsAh = (unsigned short*)zr;
  unsigned short* HsAl = (unsigned short*)(zr + NB2);
  float* cstate = (float*)(zr + 2 * NB2);

  unsigned short* HsBh = (unsigned short*)alloc(NB2);
  unsigned short* HsBl = (unsigned short*)alloc(NB2);

  unsigned short* WihH = (unsigned short*)alloc(512 * 128 * 2);
  unsigned short* WihL = (unsigned short*)alloc(512 * 128 * 2);
  unsigned short* WhhH = (unsigned short*)alloc(512 * 128 * 2);
  unsigned short* WhhL = (unsigned short*)alloc(512 * 128 * 2);
  unsigned short* W1tH = (unsigned short*)alloc(128 * 128 * 2);
  unsigned short* W1tL = (unsigned short*)alloc(128 * 128 * 2);
  unsigned short* W2tH = (unsigned short*)alloc(128 * 128 * 2);
  unsigned short* W2tL = (unsigned short*)alloc(128 * 128 * 2);
  float* bsum = (float*)alloc(512 * 4);

  k_prep<<<256, 256, 0, stream>>>(Wih, Whh, W1, W2, bih, bhh,
                                  WihH, WihL, WhhH, WhhL, W1tH, W1tL, W2tH, W2tL, bsum);
  {
    long n4 = (long)(2 * NB2 + NB4) / 16;
    k_zero4<<<(int)((n4 + 255) / 256), 256, 0, stream>>>((float4*)zr, n4);
  }

  for (int t = 0; t < TT; t++) {
    const int* erow = edges + (size_t)t * 2 * EE;
    const int* ecol = erow + EE;
    const float* xt = feats + (size_t)t * NN * 128;

    // CSR by dest + dinv
    k_zeroi<<<(NN + 255) / 256, 256, 0, stream>>>(deg, NN);
    k_count<<<EE / 256, 256, 0, stream>>>(erow, deg);
    k_scan1<<<NBLK, SCAN_B, 0, stream>>>(deg, rs, bsumP);
    k_scan2<<<1, 128, 0, stream>>>(bsumP);
    k_scan3<<<(NN + 255) / 256, 256, 0, stream>>>(rs, bsumP, deg, dinv, cursor);
    k_scatter<<<EE / 256, 256, 0, stream>>>(erow, ecol, cursor, csr);

    // GCN layer 1: feats(fp32) @ W1 -> bufH (dinv-scaled); aggregate -> bufX hi/lo
    k_gemm_mfma<0><<<391, 256, 0, stream>>>(xt, nullptr, nullptr, W1tH, W1tL, dinv, bufH);
    k_agg<<<NN / 8, 256, 0, stream>>>(bufH, dinv, rs, csr, b1, bufXh, bufXl);
    // GCN layer 2: bufX(hi/lo) @ W2 -> bufH (dinv-scaled); aggregate -> Xemb hi/lo
    k_gemm_mfma<1><<<391, 256, 0, stream>>>(nullptr, bufXh, bufXl, W2tH, W2tL, dinv, bufH);
    k_agg<<<NN / 8, 256, 0, stream>>>(bufH, dinv, rs, csr, b2, Xembh, Xembl);

    // fused LSTM step (h ping-pong)
    const unsigned short *rH, *rL;
    unsigned short *wH, *wL;
    if ((t & 1) == 0) { rH = HsAh; rL = HsAl; wH = HsBh; wL = HsBl; }
    else              { rH = HsBh; rL = HsBl; wH = HsAh; wL = HsAl; }
    k_gates_lstm<<<1563, 256, 0, stream>>>(
        Xembh, Xembl, rH, rL, WihH, WihL, WhhH, WhhL, bsum, cstate,
        wH, wL, out, (t == TT - 1) ? 1 : 0);
  }
}